// Round 9
// baseline (149510.925 us; speedup 1.0000x reference)
//
#include <hip/hip_runtime.h>

#define B_ 64
#define T_ 256
#define F_ 512
#define H_ 1024
#define O_ 512
#define NBLK 512
#define NTHR 512

#define OUT_N   (T_ * B_ * O_)        /* 8388608 */
#define NSEL_IX OUT_N
#define SEL_OFF (OUT_N + 1)

// LDS map (doubles)
#define ACI 0                 /* ci tile [4][520]  = 2080 */
#define AH  2080              /* h tile  [4][1032] = 4128 */
#define RED 6208              /* reduce buffer 2048 (shared with L-reduce) */
#define LDS_N 8256            /* 66 KB -> 2 blocks/CU */

// ---------------- device state ----------------
__device__ float4 g_W4 [(size_t)768 * 1024];    // [kpair][jj] (r0,z0,r1,z1), 12.6 MB
__device__ float2 g_Wn2[(size_t)768 * 1024];    // [kpair][jj] (n0,n1),        6.3 MB
__device__ float  g_wself[(size_t)H_ * F_];     // [k][f] f32,                 2.1 MB
__device__ double g_br[H_], g_bz[H_], g_bi[H_], g_bh[H_];
__device__ double g_bsel[F_];
__device__ double g_hb[2ull * B_ * H_];         // h double-buffer — XCD-LOCAL traffic only
__device__ unsigned g_mk[B_ * 32];              // masks [b][fchunk16] — XCD-LOCAL
__device__ float  g_hist[(size_t)T_ * B_ * H_]; // h history f32, 67 MB (plain)
__device__ unsigned g_selcnt;
__device__ unsigned g_xbar[8 * 64];             // per-XCD barrier counters (padded)
__device__ unsigned g_ticket[8 * 64];           // per-XCD slot tickets (padded)

// ---------------- helpers ----------------
__device__ __forceinline__ unsigned ld_au(const unsigned* p) {
  return __hip_atomic_load(p, __ATOMIC_RELAXED, __HIP_MEMORY_SCOPE_AGENT);
}
__device__ __forceinline__ void inv_l1() {
  asm volatile("buffer_inv" ::: "memory");   // invalidate vector L1 (XCD L2 untouched)
}

// ---------------- prep ----------------
__global__ void k_prep_w(const float* __restrict__ Wih, const float* __restrict__ Whh) {
  int i = blockIdx.x * 256 + threadIdx.x;      // 768*1024
  int kp = i >> 10, jj = i & 1023;
  int k0 = kp << 1, k1 = k0 + 1;
  float r0, z0, n0, r1, z1, n1;
  if (k0 < 512) {
    r0 = Wih[(size_t)jj * F_ + k0];  z0 = Wih[(size_t)(H_ + jj) * F_ + k0];
    n0 = Wih[(size_t)(2 * H_ + jj) * F_ + k0];
    r1 = Wih[(size_t)jj * F_ + k1];  z1 = Wih[(size_t)(H_ + jj) * F_ + k1];
    n1 = Wih[(size_t)(2 * H_ + jj) * F_ + k1];
  } else {
    int q0 = k0 - 512, q1 = k1 - 512;
    r0 = Whh[(size_t)jj * H_ + q0];  z0 = Whh[(size_t)(H_ + jj) * H_ + q0];
    n0 = Whh[(size_t)(2 * H_ + jj) * H_ + q0];
    r1 = Whh[(size_t)jj * H_ + q1];  z1 = Whh[(size_t)(H_ + jj) * H_ + q1];
    n1 = Whh[(size_t)(2 * H_ + jj) * H_ + q1];
  }
  g_W4[i]  = make_float4(r0, z0, r1, z1);
  g_Wn2[i] = make_float2(n0, n1);
}
__global__ void k_prep_wsel(const float* __restrict__ W) {  // W_sel [F, H] -> [k][f]
  int i = blockIdx.x * 256 + threadIdx.x;      // 1024*512
  int k = i >> 9, f = i & 511;
  g_wself[i] = W[(size_t)f * H_ + k];
}
__global__ void k_prep_misc(const float* __restrict__ bih,
                            const float* __restrict__ bhh,
                            const float* __restrict__ bsel,
                            float* __restrict__ out) {
  int i = blockIdx.x * 256 + threadIdx.x;      // grid 512x256 -> 131072
  if (i < 2 * B_ * H_) g_hb[i] = 0.0;
  if (i < B_ * F_) out[(size_t)SEL_OFF + i] = 1.0f;   // sel_weights[0] = ones
  if (i < B_ * 32) g_mk[i] = 0xFFFFu;                 // t=0: select everything
  if (i < H_) {
    g_br[i] = (double)bih[i] + (double)bhh[i];
    g_bz[i] = (double)bih[H_ + i] + (double)bhh[H_ + i];
    g_bi[i] = (double)bih[2 * H_ + i];
    g_bh[i] = (double)bhh[2 * H_ + i];
  }
  if (i < F_) g_bsel[i] = (double)bsel[i];
  if (i < 8 * 64) { g_xbar[i] = 0u; g_ticket[i] = 0u; }
  if (i == 0) g_selcnt = 0u;
}

// ---------------- XCD-local barrier (split arrive/wait) ----------------
__device__ __forceinline__ void xbar_arrive(unsigned xcd) {
  __builtin_amdgcn_s_waitcnt(0);
  __syncthreads();
  if (threadIdx.x == 0)
    __hip_atomic_fetch_add(&g_xbar[xcd * 64], 1u, __ATOMIC_RELAXED,
                           __HIP_MEMORY_SCOPE_AGENT);
}
__device__ __forceinline__ void xbar_wait(unsigned xcd, unsigned tgt) {
  if (threadIdx.x == 0) {
    while (ld_au(&g_xbar[xcd * 64]) < tgt) __builtin_amdgcn_s_sleep(1);
  }
  __syncthreads();
  inv_l1();
}

// ---------------- persistent time-loop kernel ----------------
// 512 blocks x 512 thr, 2 blocks/CU (LDS 66 KB). XCD g owns b in [8g,8g+8);
// its 64 blocks (slot s): jjg = s>>1 owns jj [32jjg,+32) & f [16jjg,+16);
// bh = s&1 owns b [8g+4bh, +4). All recurrent dataflow stays in the XCD's L2.
__global__ __launch_bounds__(NTHR, 4) void k_persist(const float* __restrict__ x,
                                                     const float* __restrict__ u,
                                                     float* __restrict__ out) {
  __shared__ double lds[LDS_N];
  __shared__ unsigned s_slot;
  const int tid = threadIdx.x;

  unsigned xcd_raw;
  asm("s_getreg_b32 %0, hwreg(20, 0, 32)" : "=s"(xcd_raw));   // HW_REG_XCC_ID
  const unsigned xcd = xcd_raw & 7u;
  if (tid == 0)
    s_slot = __hip_atomic_fetch_add(&g_ticket[xcd * 64], 1u, __ATOMIC_RELAXED,
                                    __HIP_MEMORY_SCOPE_AGENT);
  __syncthreads();
  const int s   = (int)(s_slot & 63u);
  const int jjg = s >> 1;              // 0..31
  const int bh  = s & 1;
  const int jj0 = jjg << 5;
  const int f0  = jjg << 4;
  const int b0  = ((int)xcd << 3) + (bh << 2);   // global batch base, 4 b per block

  // G decode: 8 waves; wave w = k-slice; lanes: (jjl 32, b4 2)
  const int w    = tid >> 6;           // 0..7
  const int lane = tid & 63;
  const int b4   = lane >> 5;          // 0,1 -> b-pair {0,1} / {2,3}
  const int jjl  = lane & 31;
  const int jj   = jj0 + jjl;

  // L decode: (lkq 8) x (lbl 4) x (lfl 16)
  const int lkq = tid >> 6;
  const int lbl = (tid >> 4) & 3;
  const int lfl = tid & 15;
  const int lf  = f0 + lfl;

  const double bs_r = g_br[jj], bs_z = g_bz[jj], bs_i = g_bi[jj], bs_h = g_bh[jj];
  const double bsel_t = g_bsel[f0 + (tid & 15)];

  for (int t = 0; t < T_; ++t) {
    const int p = t & 1;

    // ---- stage h(t-1): 4 b x 1024 k (plain loads, own-XCD L2)
    {
      const double* hb = &g_hb[((size_t)p * B_ + b0) * H_];
      #pragma unroll
      for (int it = 0; it < 8; ++it) {
        int e = it * 512 + tid;
        lds[AH + (e >> 10) * 1032 + (e & 1023)] = hb[((e >> 10) * H_) + (e & 1023)];
      }
    }
    __syncthreads();

    // ---- L: logits(h(t-1)) -> mask(t) bits (plain store, L2-local)
    if (t > 0) {
      double acc = 0.0;
      const int k0 = lkq << 7;
      const double* hrow = &lds[AH + lbl * 1032 + k0];
      const float* wp = &g_wself[(size_t)k0 * F_ + lf];
      #pragma unroll 8
      for (int ki = 0; ki < 128; ++ki) {
        acc = fma(hrow[ki], (double)wp[0], acc);
        wp += F_;
      }
      lds[RED + lkq * 64 + lbl * 16 + lfl] = acc;
      __syncthreads();
      bool wflag = false;
      if (tid < 64) {
        double sum = 0.0;
        #pragma unroll
        for (int q = 0; q < 8; ++q) sum += lds[RED + q * 64 + tid];
        int bl2 = tid >> 4;
        int ff = f0 + (tid & 15), bq = b0 + bl2;
        double logit = sum + bsel_t;
        double sig = 1.0 / (1.0 + exp(-logit));
        float uv = u[(size_t)(t * B_ + bq) * F_ + ff];
        wflag = sig > (double)uv;
        out[(size_t)SEL_OFF + (size_t)(t * B_ + bq) * F_ + ff] = wflag ? 1.0f : 0.0f;
      }
      unsigned long long bal = __ballot(wflag);
      if (tid < 64 && (tid & 15) == 0)
        g_mk[(size_t)(b0 + (tid >> 4)) * 32 + jjg] =
            (unsigned)((bal >> (tid & 48)) & 0xFFFFull);
      if (tid == 0) atomicAdd(&g_selcnt, (unsigned)__popcll(bal));
      __syncthreads();
    }

    xbar_arrive(xcd);   // barM arrive

    // ---- G (hh): k pairs [256 + w*64, +64), deep-pipelined weight stream
    double a00 = 0, a01 = 0, a10 = 0, a11 = 0;   // r, z  x (b-pair q0,q1)
    double a20 = 0, a21 = 0, a30 = 0, a31 = 0;   // in, hn
    {
      const size_t kp0 = 256 + (size_t)w * 64;
      const float4* wp4 = &g_W4 [kp0 * 1024 + jj];
      const float2* wn2 = &g_Wn2[kp0 * 1024 + jj];
      const double* hA = &lds[AH + (b4 * 2) * 1032 + (w << 7)];
      const double* hB = hA + 1032;
      float4 A0[4]; float2 C0[4];
      #pragma unroll
      for (int g = 0; g < 4; ++g) { A0[g] = wp4[(size_t)g * 1024]; C0[g] = wn2[(size_t)g * 1024]; }
      #pragma unroll
      for (int gg = 0; gg < 16; ++gg) {
        float4 A1[4]; float2 C1[4];
        if (gg < 15) {
          #pragma unroll
          for (int g = 0; g < 4; ++g) {
            A1[g] = wp4[(size_t)(gg * 4 + 4 + g) * 1024];
            C1[g] = wn2[(size_t)(gg * 4 + 4 + g) * 1024];
          }
        }
        #pragma unroll
        for (int g = 0; g < 4; ++g) {
          const int kk = (gg * 4 + g) * 2;
          double wr0 = (double)A0[g].x, wz0 = (double)A0[g].y;
          double wr1 = (double)A0[g].z, wz1 = (double)A0[g].w;
          double wn0 = (double)C0[g].x, wn1 = (double)C0[g].y;
          double h0 = hA[kk], h1 = hA[kk + 1];
          double e0 = hB[kk], e1 = hB[kk + 1];
          a00 = fma(h0, wr0, a00); a10 = fma(h0, wz0, a10); a30 = fma(h0, wn0, a30);
          a01 = fma(e0, wr0, a01); a11 = fma(e0, wz0, a11); a31 = fma(e0, wn0, a31);
          a00 = fma(h1, wr1, a00); a10 = fma(h1, wz1, a10); a30 = fma(h1, wn1, a30);
          a01 = fma(e1, wr1, a01); a11 = fma(e1, wz1, a11); a31 = fma(e1, wn1, a31);
        }
        #pragma unroll
        for (int g = 0; g < 4; ++g) { A0[g] = A1[g]; C0[g] = C1[g]; }
      }
    }

    xbar_wait(xcd, 64u * (unsigned)(2 * t + 1));   // barM wait + L1 inv

    // ---- build ci(t): 4 b x 512 k from masks x plain-cached x
    #pragma unroll
    for (int it = 0; it < 4; ++it) {
      int e = it * 512 + tid;
      int bl = e >> 9, k = e & 511;
      unsigned m = g_mk[(size_t)(b0 + bl) * 32 + (k >> 4)];
      double xd = (double)x[((size_t)(b0 + bl) * T_ + t) * F_ + k];
      lds[ACI + bl * 520 + k] = ((m >> (k & 15)) & 1u) ? xd : 0.0;
    }
    __syncthreads();

    // ---- G (gi): k pairs [w*32, +32)
    {
      const size_t kp0 = (size_t)w * 32;
      const float4* wp4 = &g_W4 [kp0 * 1024 + jj];
      const float2* wn2 = &g_Wn2[kp0 * 1024 + jj];
      const double* hA = &lds[ACI + (b4 * 2) * 520 + (w << 6)];
      const double* hB = hA + 520;
      float4 A0[4]; float2 C0[4];
      #pragma unroll
      for (int g = 0; g < 4; ++g) { A0[g] = wp4[(size_t)g * 1024]; C0[g] = wn2[(size_t)g * 1024]; }
      #pragma unroll
      for (int gg = 0; gg < 8; ++gg) {
        float4 A1[4]; float2 C1[4];
        if (gg < 7) {
          #pragma unroll
          for (int g = 0; g < 4; ++g) {
            A1[g] = wp4[(size_t)(gg * 4 + 4 + g) * 1024];
            C1[g] = wn2[(size_t)(gg * 4 + 4 + g) * 1024];
          }
        }
        #pragma unroll
        for (int g = 0; g < 4; ++g) {
          const int kk = (gg * 4 + g) * 2;
          double wr0 = (double)A0[g].x, wz0 = (double)A0[g].y;
          double wr1 = (double)A0[g].z, wz1 = (double)A0[g].w;
          double wn0 = (double)C0[g].x, wn1 = (double)C0[g].y;
          double h0 = hA[kk], h1 = hA[kk + 1];
          double e0 = hB[kk], e1 = hB[kk + 1];
          a00 = fma(h0, wr0, a00); a10 = fma(h0, wz0, a10); a20 = fma(h0, wn0, a20);
          a01 = fma(e0, wr0, a01); a11 = fma(e0, wz0, a11); a21 = fma(e0, wn0, a21);
          a00 = fma(h1, wr1, a00); a10 = fma(h1, wz1, a10); a20 = fma(h1, wn1, a20);
          a01 = fma(e1, wr1, a01); a11 = fma(e1, wz1, a11); a21 = fma(e1, wn1, a21);
        }
        #pragma unroll
        for (int g = 0; g < 4; ++g) { A0[g] = A1[g]; C0[g] = C1[g]; }
      }
    }
    __syncthreads();   // act tiles dead; LDS becomes reduce buffer

    // ---- 3-round tree reduce over the 8 k-slice waves
    double vac[4][2] = {{a00, a01}, {a10, a11}, {a20, a21}, {a30, a31}};
    #pragma unroll
    for (int half = 4; half >= 1; half >>= 1) {
      if (w >= half && w < 2 * half) {
        #pragma unroll
        for (int c = 0; c < 4; ++c)
          #pragma unroll
          for (int q = 0; q < 2; ++q)
            lds[RED + (w - half) * 512 + (c * 2 + q) * 64 + lane] = vac[c][q];
      }
      __syncthreads();
      if (w < half) {
        #pragma unroll
        for (int c = 0; c < 4; ++c)
          #pragma unroll
          for (int q = 0; q < 2; ++q)
            vac[c][q] += lds[RED + w * 512 + (c * 2 + q) * 64 + lane];
      }
      __syncthreads();
    }

    // ---- GRU update on wave 0: plain stores into g_hb[p^1] (own-XCD L2)
    if (w == 0) {
      #pragma unroll
      for (int q = 0; q < 2; ++q) {
        int b = b4 * 2 + q;
        double sr = vac[0][q] + bs_r;
        double sz = vac[1][q] + bs_z;
        double si = vac[2][q] + bs_i;
        double sh = vac[3][q] + bs_h;
        double r = 1.0 / (1.0 + exp(-sr));
        double z = 1.0 / (1.0 + exp(-sz));
        double n = tanh(si + r * sh);
        double hprev = g_hb[((size_t)p * B_ + b0 + b) * H_ + jj];
        double hnew = (1.0 - z) * n + z * hprev;
        g_hb[((size_t)(p ^ 1) * B_ + b0 + b) * H_ + jj] = hnew;
        g_hist[(size_t)t * (B_ * H_) + (size_t)(b0 + b) * H_ + jj] = (float)hnew;
      }
    }

    xbar_arrive(xcd);                               // barH arrive
    xbar_wait(xcd, 64u * (unsigned)(2 * t + 2));    // barH wait + L1 inv
  }
}

// ---------------- batched out-GEMM (f32) ----------------
__global__ __launch_bounds__(256) void k_out(const float* __restrict__ Wo,
                                             const float* __restrict__ bo,
                                             float* __restrict__ out) {
  __shared__ float sA[32][68];
  __shared__ float sB[32][68];
  const int tid = threadIdx.x;
  const int to = tid & 15, tm = tid >> 4;
  const int m0 = blockIdx.y * 64, o0 = blockIdx.x * 64;
  if (blockIdx.x == 0 && blockIdx.y == 0 && tid == 0)
    out[NSEL_IX] = (float)g_selcnt;
  float acc[4][4] = {{0.f}};
  for (int kt = 0; kt < 1024 / 32; ++kt) {
    #pragma unroll
    for (int it = 0; it < 8; ++it) {
      int e  = it * 256 + tid;
      int rl = e >> 5, kl = e & 31;
      sA[kl][rl] = g_hist[(size_t)(m0 + rl) * H_ + kt * 32 + kl];
      sB[kl][rl] = Wo[(size_t)(o0 + rl) * H_ + kt * 32 + kl];
    }
    __syncthreads();
    #pragma unroll
    for (int kl = 0; kl < 32; ++kl) {
      float a[4], bv[4];
      #pragma unroll
      for (int i = 0; i < 4; ++i) a[i] = sA[kl][tm * 4 + i];
      #pragma unroll
      for (int i = 0; i < 4; ++i) bv[i] = sB[kl][to * 4 + i];
      #pragma unroll
      for (int i = 0; i < 4; ++i)
        #pragma unroll
        for (int c = 0; c < 4; ++c)
          acc[i][c] = fmaf(a[i], bv[c], acc[i][c]);
    }
    __syncthreads();
  }
  #pragma unroll
  for (int i = 0; i < 4; ++i) {
    int m = m0 + tm * 4 + i;
    #pragma unroll
    for (int c = 0; c < 4; ++c) {
      int o = o0 + to * 4 + c;
      out[(size_t)m * O_ + o] = acc[i][c] + bo[o];
    }
  }
}

// ---------------- launcher ----------------
extern "C" void kernel_launch(void* const* d_in, const int* in_sizes, int n_in,
                              void* d_out, int out_size, void* d_ws, size_t ws_size,
                              hipStream_t stream) {
  (void)in_sizes; (void)n_in; (void)out_size; (void)d_ws; (void)ws_size;
  const float* x     = (const float*)d_in[0];
  const float* u     = (const float*)d_in[1];
  const float* W_ih  = (const float*)d_in[2];
  const float* b_ih  = (const float*)d_in[3];
  const float* W_hh  = (const float*)d_in[4];
  const float* b_hh  = (const float*)d_in[5];
  const float* W_out = (const float*)d_in[6];
  const float* b_out = (const float*)d_in[7];
  const float* W_sel = (const float*)d_in[8];
  const float* b_sel = (const float*)d_in[9];
  float* out = (float*)d_out;

  k_prep_w   <<<3072, 256, 0, stream>>>(W_ih, W_hh);
  k_prep_wsel<<<2048, 256, 0, stream>>>(W_sel);
  k_prep_misc<<<512, 256, 0, stream>>>(b_ih, b_hh, b_sel, out);

  k_persist<<<NBLK, NTHR, 0, stream>>>(x, u, out);

  k_out<<<dim3(8, 256), 256, 0, stream>>>(W_out, b_out, out);
}

// Round 10
// 113760.059 us; speedup vs baseline: 1.3143x; 1.3143x over previous
//
#include <hip/hip_runtime.h>

#define B_ 64
#define T_ 256
#define F_ 512
#define H_ 1024
#define O_ 512
#define NBLK 256
#define NTHR 1024

#define OUT_N   (T_ * B_ * O_)        /* 8388608 */
#define NSEL_IX OUT_N
#define SEL_OFF (OUT_N + 1)

// LDS map (doubles): [b][k] layouts, padded strides
#define ACI 0                 /* ci tile  [8][520]  */
#define AH  4160              /* h tile   [8][1032] */
#define LDS_N 12416           /* 99.3 KB -> exactly 1 block/CU */

// ---------------- device state ----------------
__device__ float4 g_W4 [(size_t)768 * 1024];    // [kpair][jj] (r0,z0,r1,z1), 12.6 MB
__device__ float2 g_Wn2[(size_t)768 * 1024];    // [kpair][jj] (n0,n1),        6.3 MB
__device__ float  g_wself[(size_t)H_ * F_];     // [k][f] f32,                 2.1 MB
__device__ double g_br[H_], g_bz[H_], g_bi[H_], g_bh[H_];
__device__ double g_bsel[F_];
__device__ double g_hb[2ull * B_ * H_];         // h double-buffer — XCD-LOCAL traffic only
__device__ unsigned g_mk[B_ * 32];              // masks [b][fchunk16] — XCD-LOCAL
__device__ float  g_hist[(size_t)T_ * B_ * H_]; // h history f32, 67 MB (plain)
__device__ unsigned g_selcnt;
__device__ unsigned g_xbar[8 * 64];             // per-XCD barrier counters (padded)
__device__ unsigned g_ticket[8 * 64];           // per-XCD slot tickets (padded)

// ---------------- helpers ----------------
__device__ __forceinline__ unsigned ld_au(const unsigned* p) {
  return __hip_atomic_load(p, __ATOMIC_RELAXED, __HIP_MEMORY_SCOPE_AGENT);
}
__device__ __forceinline__ void inv_l1() {
  asm volatile("buffer_inv" ::: "memory");   // invalidate vector L1 (XCD L2 untouched)
}

// ---------------- prep ----------------
__global__ void k_prep_w(const float* __restrict__ Wih, const float* __restrict__ Whh) {
  int i = blockIdx.x * 256 + threadIdx.x;      // 768*1024
  int kp = i >> 10, jj = i & 1023;
  int k0 = kp << 1, k1 = k0 + 1;
  float r0, z0, n0, r1, z1, n1;
  if (k0 < 512) {
    r0 = Wih[(size_t)jj * F_ + k0];  z0 = Wih[(size_t)(H_ + jj) * F_ + k0];
    n0 = Wih[(size_t)(2 * H_ + jj) * F_ + k0];
    r1 = Wih[(size_t)jj * F_ + k1];  z1 = Wih[(size_t)(H_ + jj) * F_ + k1];
    n1 = Wih[(size_t)(2 * H_ + jj) * F_ + k1];
  } else {
    int q0 = k0 - 512, q1 = k1 - 512;
    r0 = Whh[(size_t)jj * H_ + q0];  z0 = Whh[(size_t)(H_ + jj) * H_ + q0];
    n0 = Whh[(size_t)(2 * H_ + jj) * H_ + q0];
    r1 = Whh[(size_t)jj * H_ + q1];  z1 = Whh[(size_t)(H_ + jj) * H_ + q1];
    n1 = Whh[(size_t)(2 * H_ + jj) * H_ + q1];
  }
  g_W4[i]  = make_float4(r0, z0, r1, z1);
  g_Wn2[i] = make_float2(n0, n1);
}
__global__ void k_prep_wsel(const float* __restrict__ W) {  // W_sel [F, H] -> [k][f]
  int i = blockIdx.x * 256 + threadIdx.x;      // 1024*512
  int k = i >> 9, f = i & 511;
  g_wself[i] = W[(size_t)f * H_ + k];
}
__global__ void k_prep_misc(const float* __restrict__ bih,
                            const float* __restrict__ bhh,
                            const float* __restrict__ bsel,
                            float* __restrict__ out) {
  int i = blockIdx.x * 256 + threadIdx.x;      // grid 512x256 -> 131072
  if (i < 2 * B_ * H_) g_hb[i] = 0.0;
  if (i < B_ * F_) out[(size_t)SEL_OFF + i] = 1.0f;   // sel_weights[0] = ones
  if (i < B_ * 32) g_mk[i] = 0xFFFFu;                 // t=0: select everything
  if (i < H_) {
    g_br[i] = (double)bih[i] + (double)bhh[i];
    g_bz[i] = (double)bih[H_ + i] + (double)bhh[H_ + i];
    g_bi[i] = (double)bih[2 * H_ + i];
    g_bh[i] = (double)bhh[2 * H_ + i];
  }
  if (i < F_) g_bsel[i] = (double)bsel[i];
  if (i < 8 * 64) { g_xbar[i] = 0u; g_ticket[i] = 0u; }
  if (i == 0) g_selcnt = 0u;
}

// ---------------- XCD-local barrier (split arrive/wait) ----------------
__device__ __forceinline__ void xbar_arrive(unsigned xcd) {
  __builtin_amdgcn_s_waitcnt(0);
  __syncthreads();
  if (threadIdx.x == 0)
    __hip_atomic_fetch_add(&g_xbar[xcd * 64], 1u, __ATOMIC_RELAXED,
                           __HIP_MEMORY_SCOPE_AGENT);
}
__device__ __forceinline__ void xbar_wait(unsigned xcd, unsigned tgt) {
  if (threadIdx.x == 0) {
    while (ld_au(&g_xbar[xcd * 64]) < tgt) __builtin_amdgcn_s_sleep(1);
  }
  __syncthreads();
  inv_l1();
}

// ---- one k-pair of gate FMAs: named weight regs, 4 b's, r/z/(target) channels
#define KP(Wv, Nv, AP, STRIDE, KK, T0, T1, T2, T3)                              \
  { double wr0 = (double)(Wv).x, wz0 = (double)(Wv).y;                          \
    double wr1 = (double)(Wv).z, wz1 = (double)(Wv).w;                          \
    double wn0 = (double)(Nv).x, wn1 = (double)(Nv).y;                          \
    double h00 = (AP)[(KK)],                h01 = (AP)[(KK) + 1];               \
    double h10 = (AP)[(STRIDE) + (KK)],     h11 = (AP)[(STRIDE) + (KK) + 1];    \
    double h20 = (AP)[2*(STRIDE) + (KK)],   h21 = (AP)[2*(STRIDE) + (KK) + 1];  \
    double h30 = (AP)[3*(STRIDE) + (KK)],   h31 = (AP)[3*(STRIDE) + (KK) + 1];  \
    aR0 = fma(h00, wr0, aR0); aR0 = fma(h01, wr1, aR0);                         \
    aR1 = fma(h10, wr0, aR1); aR1 = fma(h11, wr1, aR1);                         \
    aR2 = fma(h20, wr0, aR2); aR2 = fma(h21, wr1, aR2);                         \
    aR3 = fma(h30, wr0, aR3); aR3 = fma(h31, wr1, aR3);                         \
    aZ0 = fma(h00, wz0, aZ0); aZ0 = fma(h01, wz1, aZ0);                         \
    aZ1 = fma(h10, wz0, aZ1); aZ1 = fma(h11, wz1, aZ1);                         \
    aZ2 = fma(h20, wz0, aZ2); aZ2 = fma(h21, wz1, aZ2);                         \
    aZ3 = fma(h30, wz0, aZ3); aZ3 = fma(h31, wz1, aZ3);                         \
    T0  = fma(h00, wn0, T0);  T0  = fma(h01, wn1, T0);                          \
    T1  = fma(h10, wn0, T1);  T1  = fma(h11, wn1, T1);                          \
    T2  = fma(h20, wn0, T2);  T2  = fma(h21, wn1, T2);                          \
    T3  = fma(h30, wn0, T3);  T3  = fma(h31, wn1, T3); }

// ---- 8 k-pairs: 16 named weight loads issued up-front (deep MLP), then FMAs
#define GROUP8(WP, NP, AP, STRIDE, KB, T0, T1, T2, T3)                          \
  { float4 W0 = (WP)[0],        W1 = (WP)[1024],     W2 = (WP)[2 * 1024];       \
    float4 W3 = (WP)[3 * 1024], Wv4 = (WP)[4 * 1024], W5 = (WP)[5 * 1024];      \
    float4 W6 = (WP)[6 * 1024], W7 = (WP)[7 * 1024];                            \
    float2 N0 = (NP)[0],        N1 = (NP)[1024],     N2 = (NP)[2 * 1024];       \
    float2 N3 = (NP)[3 * 1024], N4 = (NP)[4 * 1024], N5 = (NP)[5 * 1024];       \
    float2 N6 = (NP)[6 * 1024], N7 = (NP)[7 * 1024];                            \
    KP(W0, N0, AP, STRIDE, (KB) + 0,  T0, T1, T2, T3)                           \
    KP(W1, N1, AP, STRIDE, (KB) + 2,  T0, T1, T2, T3)                           \
    KP(W2, N2, AP, STRIDE, (KB) + 4,  T0, T1, T2, T3)                           \
    KP(W3, N3, AP, STRIDE, (KB) + 6,  T0, T1, T2, T3)                           \
    KP(Wv4, N4, AP, STRIDE, (KB) + 8, T0, T1, T2, T3)                           \
    KP(W5, N5, AP, STRIDE, (KB) + 10, T0, T1, T2, T3)                           \
    KP(W6, N6, AP, STRIDE, (KB) + 12, T0, T1, T2, T3)                           \
    KP(W7, N7, AP, STRIDE, (KB) + 14, T0, T1, T2, T3) }

// ---------------- persistent time-loop kernel ----------------
// 256 blocks x 1024 thr, 1 block/CU. XCD g owns b in [8g,8g+8); its 32 blocks
// (slot s): jj in [32s,+32), f in [16s,+16). All recurrent dataflow XCD-local.
__global__ __launch_bounds__(NTHR, 4) void k_persist(const float* __restrict__ x,
                                                     const float* __restrict__ u,
                                                     float* __restrict__ out) {
  __shared__ double lds[LDS_N];
  __shared__ unsigned s_slot;
  const int tid = threadIdx.x;

  unsigned xcd_raw;
  asm("s_getreg_b32 %0, hwreg(20, 0, 32)" : "=s"(xcd_raw));   // HW_REG_XCC_ID
  const unsigned xcd = xcd_raw & 7u;
  if (tid == 0)
    s_slot = __hip_atomic_fetch_add(&g_ticket[xcd * 64], 1u, __ATOMIC_RELAXED,
                                    __HIP_MEMORY_SCOPE_AGENT);
  __syncthreads();
  const int s   = (int)(s_slot & 31u);
  const int jj0 = s << 5;
  const int f0  = s << 4;
  const int b0  = (int)xcd << 3;

  // G decode: 16 waves; wave w = k-slice; lanes: (b4 2) x (jjl 32)
  const int w    = tid >> 6;           // 0..15
  const int lane = tid & 63;
  const int b4   = lane >> 5;          // 0,1 -> b-halves {0-3},{4-7}
  const int jjl  = lane & 31;
  const int jj   = jj0 + jjl;

  // L decode: (lkq 8) x (lbl 8) x (lfl 16)
  const int lkq = tid >> 7;
  const int lbl = (tid >> 4) & 7;
  const int lfl = tid & 15;
  const int lf  = f0 + lfl;

  double bs_r = 0, bs_z = 0, bs_i = 0, bs_h = 0;
  if (w == 0) { bs_r = g_br[jj]; bs_z = g_bz[jj]; bs_i = g_bi[jj]; bs_h = g_bh[jj]; }
  const double bsel_t = g_bsel[f0 + (tid & 15)];

  for (int t = 0; t < T_; ++t) {
    const int p = t & 1;

    // ---- stage h(t-1): 8 b x 1024 k (plain loads, own-XCD L2)
    {
      const double* hb = &g_hb[((size_t)p * B_ + b0) * H_];
      #pragma unroll
      for (int it = 0; it < 8; ++it) {
        int e = it * 1024 + tid;
        lds[AH + (e >> 10) * 1032 + (e & 1023)] = hb[e];
      }
    }
    __syncthreads();

    // ---- L: logits(h(t-1)) -> mask(t) bits; 4 independent acc chains, unroll 8
    if (t > 0) {
      double ac0 = 0, ac1 = 0, ac2 = 0, ac3 = 0;
      const int k0 = lkq << 7;
      const double* hrow = &lds[AH + lbl * 1032 + k0];
      const float* wp = &g_wself[(size_t)k0 * F_ + lf];
      #pragma unroll 8
      for (int ki = 0; ki < 128; ki += 4) {
        ac0 = fma(hrow[ki],     (double)wp[0],      ac0);
        ac1 = fma(hrow[ki + 1], (double)wp[F_],     ac1);
        ac2 = fma(hrow[ki + 2], (double)wp[2 * F_], ac2);
        ac3 = fma(hrow[ki + 3], (double)wp[3 * F_], ac3);
        wp += 4 * F_;
      }
      lds[lkq * 128 + lbl * 16 + lfl] = (ac0 + ac1) + (ac2 + ac3);
      __syncthreads();
      bool wflag = false;
      if (tid < 128) {
        double sum = 0.0;
        #pragma unroll
        for (int q = 0; q < 8; ++q) sum += lds[q * 128 + tid];
        int bl2 = tid >> 4;
        int ff = f0 + (tid & 15), bq = b0 + bl2;
        double logit = sum + bsel_t;
        double sig = 1.0 / (1.0 + exp(-logit));
        float uv = u[(size_t)(t * B_ + bq) * F_ + ff];
        wflag = sig > (double)uv;
        out[(size_t)SEL_OFF + (size_t)(t * B_ + bq) * F_ + ff] = wflag ? 1.0f : 0.0f;
      }
      unsigned long long bal = __ballot(wflag);
      if (tid < 128) {
        if ((tid & 15) == 0)
          g_mk[(size_t)(b0 + (tid >> 4)) * 32 + s] =
              (unsigned)((bal >> (tid & 48)) & 0xFFFFull);
        if ((tid & 63) == 0)
          atomicAdd(&g_selcnt, (unsigned)__popcll(bal));
      }
    }

    xbar_arrive(xcd);   // barM arrive

    // ---- G (hh): k-pairs [256 + w*32, +32) in 4 groups of 8 (deep-pipelined)
    double aR0 = 0, aR1 = 0, aR2 = 0, aR3 = 0;
    double aZ0 = 0, aZ1 = 0, aZ2 = 0, aZ3 = 0;
    double aI0 = 0, aI1 = 0, aI2 = 0, aI3 = 0;
    double aN0 = 0, aN1 = 0, aN2 = 0, aN3 = 0;
    {
      const float4* wp4 = &g_W4 [(size_t)(256 + (w << 5)) * 1024 + jj];
      const float2* wn2 = &g_Wn2[(size_t)(256 + (w << 5)) * 1024 + jj];
      const double* ap0 = &lds[AH + (b4 * 4) * 1032];
      const int kb = w << 6;
      GROUP8(wp4,             wn2,             ap0, 1032, kb,      aN0, aN1, aN2, aN3)
      GROUP8(wp4 +  8 * 1024, wn2 +  8 * 1024, ap0, 1032, kb + 16, aN0, aN1, aN2, aN3)
      GROUP8(wp4 + 16 * 1024, wn2 + 16 * 1024, ap0, 1032, kb + 32, aN0, aN1, aN2, aN3)
      GROUP8(wp4 + 24 * 1024, wn2 + 24 * 1024, ap0, 1032, kb + 48, aN0, aN1, aN2, aN3)
    }

    xbar_wait(xcd, 32u * (unsigned)(2 * t + 1));   // barM wait + L1 inv

    // ---- build ci(t): 8 b x 512 k from XCD-local masks x plain-cached x
    #pragma unroll
    for (int it = 0; it < 4; ++it) {
      int e = it * 1024 + tid;
      int bl = e >> 9, k = e & 511;
      unsigned m = g_mk[(size_t)(b0 + bl) * 32 + (k >> 4)];
      double xd = (double)x[((size_t)(b0 + bl) * T_ + t) * F_ + k];
      lds[ACI + bl * 520 + k] = ((m >> (k & 15)) & 1u) ? xd : 0.0;
    }
    __syncthreads();

    // ---- G (gi): k-pairs [w*16, +16) in 2 groups of 8
    {
      const float4* wp4 = &g_W4 [(size_t)(w << 4) * 1024 + jj];
      const float2* wn2 = &g_Wn2[(size_t)(w << 4) * 1024 + jj];
      const double* ap0 = &lds[ACI + (b4 * 4) * 520];
      const int kb = w << 5;
      GROUP8(wp4,            wn2,            ap0, 520, kb,      aI0, aI1, aI2, aI3)
      GROUP8(wp4 + 8 * 1024, wn2 + 8 * 1024, ap0, 520, kb + 16, aI0, aI1, aI2, aI3)
    }
    __syncthreads();   // act tiles dead; LDS becomes reduce buffer

    // ---- 4-round tree reduce over the 16 k-slice waves
    double vac[4][4] = {{aR0, aR1, aR2, aR3}, {aZ0, aZ1, aZ2, aZ3},
                        {aI0, aI1, aI2, aI3}, {aN0, aN1, aN2, aN3}};
    #pragma unroll
    for (int half = 8; half >= 1; half >>= 1) {
      if (w >= half && w < 2 * half) {
        #pragma unroll
        for (int c = 0; c < 4; ++c)
          #pragma unroll
          for (int q = 0; q < 4; ++q)
            lds[((w - half) * 4 + c) * 256 + (b4 * 4 + q) * 32 + jjl] = vac[c][q];
      }
      __syncthreads();
      if (w < half) {
        #pragma unroll
        for (int c = 0; c < 4; ++c)
          #pragma unroll
          for (int q = 0; q < 4; ++q)
            vac[c][q] += lds[(w * 4 + c) * 256 + (b4 * 4 + q) * 32 + jjl];
      }
      __syncthreads();
    }

    // ---- GRU update on wave 0: plain stores into g_hb[p^1] (own-XCD L2)
    if (w == 0) {
      #pragma unroll
      for (int q = 0; q < 4; ++q) {
        int b = b4 * 4 + q;
        double sr = vac[0][q] + bs_r;
        double sz = vac[1][q] + bs_z;
        double si = vac[2][q] + bs_i;
        double sh = vac[3][q] + bs_h;
        double r = 1.0 / (1.0 + exp(-sr));
        double z = 1.0 / (1.0 + exp(-sz));
        double n = tanh(si + r * sh);
        double hprev = g_hb[((size_t)p * B_ + b0 + b) * H_ + jj];
        double hnew = (1.0 - z) * n + z * hprev;
        g_hb[((size_t)(p ^ 1) * B_ + b0 + b) * H_ + jj] = hnew;
        g_hist[(size_t)t * (B_ * H_) + (size_t)(b0 + b) * H_ + jj] = (float)hnew;
      }
    }

    xbar_arrive(xcd);                               // barH arrive
    xbar_wait(xcd, 32u * (unsigned)(2 * t + 2));    // barH wait + L1 inv
  }
}

// ---------------- batched out-GEMM (f32) ----------------
__global__ __launch_bounds__(256) void k_out(const float* __restrict__ Wo,
                                             const float* __restrict__ bo,
                                             float* __restrict__ out) {
  __shared__ float sA[32][68];
  __shared__ float sB[32][68];
  const int tid = threadIdx.x;
  const int to = tid & 15, tm = tid >> 4;
  const int m0 = blockIdx.y * 64, o0 = blockIdx.x * 64;
  if (blockIdx.x == 0 && blockIdx.y == 0 && tid == 0)
    out[NSEL_IX] = (float)g_selcnt;
  float acc[4][4] = {{0.f}};
  for (int kt = 0; kt < 1024 / 32; ++kt) {
    #pragma unroll
    for (int it = 0; it < 8; ++it) {
      int e  = it * 256 + tid;
      int rl = e >> 5, kl = e & 31;
      sA[kl][rl] = g_hist[(size_t)(m0 + rl) * H_ + kt * 32 + kl];
      sB[kl][rl] = Wo[(size_t)(o0 + rl) * H_ + kt * 32 + kl];
    }
    __syncthreads();
    #pragma unroll
    for (int kl = 0; kl < 32; ++kl) {
      float a[4], bv[4];
      #pragma unroll
      for (int i = 0; i < 4; ++i) a[i] = sA[kl][tm * 4 + i];
      #pragma unroll
      for (int i = 0; i < 4; ++i) bv[i] = sB[kl][to * 4 + i];
      #pragma unroll
      for (int i = 0; i < 4; ++i)
        #pragma unroll
        for (int c = 0; c < 4; ++c)
          acc[i][c] = fmaf(a[i], bv[c], acc[i][c]);
    }
    __syncthreads();
  }
  #pragma unroll
  for (int i = 0; i < 4; ++i) {
    int m = m0 + tm * 4 + i;
    #pragma unroll
    for (int c = 0; c < 4; ++c) {
      int o = o0 + to * 4 + c;
      out[(size_t)m * O_ + o] = acc[i][c] + bo[o];
    }
  }
}

// ---------------- launcher ----------------
extern "C" void kernel_launch(void* const* d_in, const int* in_sizes, int n_in,
                              void* d_out, int out_size, void* d_ws, size_t ws_size,
                              hipStream_t stream) {
  (void)in_sizes; (void)n_in; (void)out_size; (void)d_ws; (void)ws_size;
  const float* x     = (const float*)d_in[0];
  const float* u     = (const float*)d_in[1];
  const float* W_ih  = (const float*)d_in[2];
  const float* b_ih  = (const float*)d_in[3];
  const float* W_hh  = (const float*)d_in[4];
  const float* b_hh  = (const float*)d_in[5];
  const float* W_out = (const float*)d_in[6];
  const float* b_out = (const float*)d_in[7];
  const float* W_sel = (const float*)d_in[8];
  const float* b_sel = (const float*)d_in[9];
  float* out = (float*)d_out;

  k_prep_w   <<<3072, 256, 0, stream>>>(W_ih, W_hh);
  k_prep_wsel<<<2048, 256, 0, stream>>>(W_sel);
  k_prep_misc<<<512, 256, 0, stream>>>(b_ih, b_hh, b_sel, out);

  k_persist<<<NBLK, NTHR, 0, stream>>>(x, u, out);

  k_out<<<dim3(8, 256), 256, 0, stream>>>(W_out, b_out, out);
}